// Round 1
// baseline (4449.607 us; speedup 1.0000x reference)
//
#include <hip/hip_runtime.h>
#include <hip/hip_bf16.h>
#include <math.h>

#define NN 4
#define CC 1024
#define DD 768
#define HH 12
#define EE 32
#define MM 4
#define PP 256
#define EMBD 768
#define BSZ 64
#define NCLS 97
#define NP (NN*PP)      // 1024
#define K2D (2*DD)      // 1536
#define OFFS 1

__device__ __forceinline__ float blockReduceSum(float v) {
  #pragma unroll
  for (int off = 32; off > 0; off >>= 1) v += __shfl_down(v, off, 64);
  __shared__ float red_s[8];
  int wid = threadIdx.x >> 6, lane = threadIdx.x & 63;
  int nw = (blockDim.x + 63) >> 6;
  if (lane == 0) red_s[wid] = v;
  __syncthreads();
  if (threadIdx.x == 0) {
    float s = 0.f;
    for (int i = 0; i < nw; ++i) s += red_s[i];
    red_s[0] = s;
  }
  __syncthreads();
  float r = red_s[0];
  __syncthreads();
  return r;
}

// K1: e_emb (logsumexp over valid mentions) + cnt + valid bitmask
__global__ __launch_bounds__(256) void k_entity(const float* __restrict__ seq,
                                                const int* __restrict__ midx,
                                                const unsigned char* __restrict__ mask,
                                                float* __restrict__ e_emb,
                                                float* __restrict__ cntv,
                                                int* __restrict__ vbuf) {
  int ne = blockIdx.x;
  int n = ne / EE;
  __shared__ int pos_s[MM];
  __shared__ int val_s[MM];
  if (threadIdx.x == 0) {
    // detect mask storage: 1-byte bool => every int32 word of first 512B is odd
    const int* wm = (const int*)mask;
    int allodd = 1;
    for (int i = 0; i < NN * EE; ++i) {
      if ((wm[i] & 1) == 0) { allodd = 0; break; }
    }
    int vb = 0, cnt = 0;
    for (int m = 0; m < MM; ++m) {
      int idx = midx[ne * MM + m];
      int p = idx + OFFS; if (p > CC - 1) p = CC - 1;
      pos_s[m] = p;
      int v = allodd ? (mask[ne * MM + m] != 0) : (wm[ne * MM + m] != 0);
      val_s[m] = v;
      if (v) { vb |= (1 << m); cnt++; }
    }
    cntv[ne] = (float)cnt;
    vbuf[ne] = vb;
  }
  __syncthreads();
  const float* sb = seq + (size_t)n * CC * DD;
  for (int d = threadIdx.x; d < DD; d += 256) {
    float x[MM];
    float mx = -1e30f;
    #pragma unroll
    for (int m = 0; m < MM; ++m) {
      x[m] = val_s[m] ? sb[(size_t)pos_s[m] * DD + d] : 0.f;
      if (val_s[m]) mx = fmaxf(mx, x[m]);
    }
    float s = 0.f;
    #pragma unroll
    for (int m = 0; m < MM; ++m) {
      if (val_s[m]) s += expf(x[m] - mx);
    }
    e_emb[(size_t)ne * DD + d] = mx + logf(s);
  }
}

// K2: e_att[n][e][h][c] = (1/cnt) * sum_valid att[n,h,pos,c]
__global__ __launch_bounds__(256) void k_eatt(const float* __restrict__ att,
                                              const int* __restrict__ midx,
                                              const float* __restrict__ cntv,
                                              const int* __restrict__ vbuf,
                                              float* __restrict__ e_att) {
  int b = blockIdx.x;
  int n = b / (EE * HH);
  int rem = b % (EE * HH);
  int e = rem / HH, h = rem % HH;
  int ne = n * EE + e;
  __shared__ int pos_s[MM];
  __shared__ int nv_s;
  __shared__ float inv_s;
  if (threadIdx.x == 0) {
    int vb = vbuf[ne];
    int cp = 0;
    for (int m = 0; m < MM; ++m) {
      if (vb & (1 << m)) {
        int p = midx[ne * MM + m] + OFFS; if (p > CC - 1) p = CC - 1;
        pos_s[cp++] = p;
      }
    }
    nv_s = cp;
    inv_s = 1.f / cntv[ne];
  }
  __syncthreads();
  const float* ab = att + ((size_t)n * HH + h) * CC * CC;
  float* ob = e_att + ((size_t)ne * HH + h) * CC;
  int nv = nv_s;
  float inv = inv_s;
  for (int c = threadIdx.x; c < CC; c += 256) {
    float s = 0.f;
    for (int m = 0; m < nv; ++m) s += ab[(size_t)pos_s[m] * CC + c];
    ob[c] = s * inv;
  }
}

// K3: ht[n][p][c] = normalize_c( mean_h(h_att * t_att) )
__global__ __launch_bounds__(256) void k_ht(const float* __restrict__ e_att,
                                            const int* __restrict__ pairs,
                                            float* __restrict__ ht) {
  int np = blockIdx.x;
  int n = np >> 8;  // P=256
  int tid = threadIdx.x;
  int ph = pairs[np * 2], pt = pairs[np * 2 + 1];
  const float* ha = e_att + ((size_t)(n * EE + ph)) * HH * CC;
  const float* ta = e_att + ((size_t)(n * EE + pt)) * HH * CC;
  float v[4];
  float lsum = 0.f;
  #pragma unroll
  for (int i = 0; i < 4; ++i) {
    int c = tid + i * 256;
    float s = 0.f;
    #pragma unroll
    for (int h = 0; h < HH; ++h) s += ha[(size_t)h * CC + c] * ta[(size_t)h * CC + c];
    s *= (1.f / HH);
    v[i] = s;
    lsum += s;
  }
  float tot = blockReduceSum(lsum);
  float inv = 1.f / (tot + 1e-5f);
  #pragma unroll
  for (int i = 0; i < 4; ++i) ht[(size_t)np * CC + tid + i * 256] = v[i] * inv;
}

// K4: rs = ht @ seq; build X_h = [hs | rs], X_t = [ts | rs]
__global__ __launch_bounds__(256) void k_rs(const float* __restrict__ ht,
                                            const float* __restrict__ seq,
                                            const float* __restrict__ e_emb,
                                            const int* __restrict__ pairs,
                                            float* __restrict__ xh,
                                            float* __restrict__ xt) {
  int np = blockIdx.x;
  int n = np >> 8;
  int tid = threadIdx.x;
  __shared__ float hts[CC];
  for (int c = tid; c < CC; c += 256) hts[c] = ht[(size_t)np * CC + c];
  __syncthreads();
  int ph = pairs[np * 2], pt = pairs[np * 2 + 1];
  const float* he = e_emb + (size_t)(n * EE + ph) * DD;
  const float* te = e_emb + (size_t)(n * EE + pt) * DD;
  const float* sb = seq + (size_t)n * CC * DD;
  float acc0 = 0.f, acc1 = 0.f, acc2 = 0.f;
  for (int c = 0; c < CC; ++c) {
    float hv = hts[c];
    const float* s = sb + (size_t)c * DD + tid;
    acc0 += hv * s[0];
    acc1 += hv * s[256];
    acc2 += hv * s[512];
  }
  size_t base = (size_t)np * K2D;
  xh[base + DD + tid]       = acc0; xt[base + DD + tid]       = acc0;
  xh[base + DD + tid + 256] = acc1; xt[base + DD + tid + 256] = acc1;
  xh[base + DD + tid + 512] = acc2; xt[base + DD + tid + 512] = acc2;
  xh[base + tid]       = he[tid];       xt[base + tid]       = te[tid];
  xh[base + tid + 256] = he[tid + 256]; xt[base + tid + 256] = te[tid + 256];
  xh[base + tid + 512] = he[tid + 512]; xt[base + tid + 512] = te[tid + 512];
}

// K5: out = tanh(A(1024x1536) @ W(1536x768) + b)
__global__ __launch_bounds__(256) void k_gemm_tanh(const float* __restrict__ A,
                                                   const float* __restrict__ W,
                                                   const float* __restrict__ bias,
                                                   float* __restrict__ out) {
  __shared__ float As[64][17];
  __shared__ float Ws[16][64];
  int r0 = blockIdx.x * 64, o0 = blockIdx.y * 64;
  int tid = threadIdx.x;
  int tx = tid & 15, ty = tid >> 4;
  float acc[4][4] = {};
  for (int k0 = 0; k0 < K2D; k0 += 16) {
    __syncthreads();
    #pragma unroll
    for (int i = tid; i < 64 * 16; i += 256) {
      int rr = i >> 4, kk = i & 15;
      As[rr][kk] = A[(size_t)(r0 + rr) * K2D + k0 + kk];
    }
    #pragma unroll
    for (int i = tid; i < 16 * 64; i += 256) {
      int kk = i >> 6, oo = i & 63;
      Ws[kk][oo] = W[(size_t)(k0 + kk) * EMBD + o0 + oo];
    }
    __syncthreads();
    #pragma unroll
    for (int kk = 0; kk < 16; ++kk) {
      float a[4];
      #pragma unroll
      for (int rr = 0; rr < 4; ++rr) a[rr] = As[ty * 4 + rr][kk];
      float4 wv = *(const float4*)&Ws[kk][tx * 4];
      float wb[4] = {wv.x, wv.y, wv.z, wv.w};
      #pragma unroll
      for (int rr = 0; rr < 4; ++rr)
        #pragma unroll
        for (int oo = 0; oo < 4; ++oo)
          acc[rr][oo] += a[rr] * wb[oo];
    }
  }
  #pragma unroll
  for (int rr = 0; rr < 4; ++rr) {
    int r = r0 + ty * 4 + rr;
    #pragma unroll
    for (int oo = 0; oo < 4; ++oo) {
      int o = o0 + tx * 4 + oo;
      out[(size_t)r * EMBD + o] = tanhf(acc[rr][oo] + bias[o]);
    }
  }
}

// K6: group bilinear emb[r,o] = sum_{k,i,j} b1[r,k,i] b2[r,k,j] W[k,i,j,o] + b[o]
__global__ __launch_bounds__(256) void k_bilinear(const float* __restrict__ hs2,
                                                  const float* __restrict__ ts2,
                                                  const float* __restrict__ bilW,
                                                  const float* __restrict__ bilb,
                                                  float* __restrict__ embv) {
  __shared__ float b2s[64][65];
  __shared__ float b1s[64][65];
  __shared__ float Ws[64][64];
  int r0 = blockIdx.x * 64, o0 = blockIdx.y * 64;
  int tid = threadIdx.x;
  int tx = tid & 15, ty = tid >> 4;
  float acc[4][4] = {};
  for (int k = 0; k < EMBD / BSZ; ++k) {  // 12 groups
    __syncthreads();
    for (int i = tid; i < 64 * 64; i += 256) {
      int rr = i >> 6, j = i & 63;
      b2s[rr][j] = ts2[(size_t)(r0 + rr) * EMBD + k * 64 + j];
      b1s[rr][j] = hs2[(size_t)(r0 + rr) * EMBD + k * 64 + j];
    }
    for (int ii = 0; ii < 64; ++ii) {
      __syncthreads();
      for (int i = tid; i < 64 * 64; i += 256) {
        int jj = i >> 6, oo = i & 63;
        Ws[jj][oo] = bilW[((size_t)(k * 4096 + ii * 64 + jj)) * EMBD + o0 + oo];
      }
      __syncthreads();
      float s[4][4] = {};
      #pragma unroll 8
      for (int j = 0; j < 64; ++j) {
        float bv[4];
        #pragma unroll
        for (int rr = 0; rr < 4; ++rr) bv[rr] = b2s[ty * 4 + rr][j];
        float4 wv = *(const float4*)&Ws[j][tx * 4];
        float wb[4] = {wv.x, wv.y, wv.z, wv.w};
        #pragma unroll
        for (int rr = 0; rr < 4; ++rr)
          #pragma unroll
          for (int oo = 0; oo < 4; ++oo)
            s[rr][oo] += bv[rr] * wb[oo];
      }
      #pragma unroll
      for (int rr = 0; rr < 4; ++rr) {
        float b1v = b1s[ty * 4 + rr][ii];
        #pragma unroll
        for (int oo = 0; oo < 4; ++oo) acc[rr][oo] += b1v * s[rr][oo];
      }
    }
  }
  #pragma unroll
  for (int rr = 0; rr < 4; ++rr) {
    int r = r0 + ty * 4 + rr;
    #pragma unroll
    for (int oo = 0; oo < 4; ++oo) {
      int o = o0 + tx * 4 + oo;
      embv[(size_t)r * EMBD + o] = acc[rr][oo] + bilb[o];
    }
  }
}

// K7: rn = l2norm(r_emb_table @ re_W + re_b)
__global__ __launch_bounds__(256) void k_rel(const float* __restrict__ remb,
                                             const float* __restrict__ reW,
                                             const float* __restrict__ reb,
                                             float* __restrict__ rn) {
  int c = blockIdx.x;
  __shared__ float row_s[DD];
  int tid = threadIdx.x;
  for (int d = tid; d < DD; d += 256) row_s[d] = remb[(size_t)c * DD + d];
  __syncthreads();
  float v[3];
  float ss = 0.f;
  #pragma unroll
  for (int i = 0; i < 3; ++i) {
    int j = tid + i * 256;
    float acc = reb[j];
    for (int d = 0; d < DD; ++d) acc += row_s[d] * reW[(size_t)d * EMBD + j];
    v[i] = acc;
    ss += acc * acc;
  }
  float tot = blockReduceSum(ss);
  float scale = 1.f / fmaxf(sqrtf(tot), 1e-12f);
  #pragma unroll
  for (int i = 0; i < 3; ++i) rn[(size_t)c * EMBD + tid + i * 256] = v[i] * scale;
}

// K8: logits[r,c] = l2norm(emb[r]) . rn[c]
__global__ __launch_bounds__(128) void k_logits(const float* __restrict__ embv,
                                                const float* __restrict__ rn,
                                                float* __restrict__ out) {
  int r = blockIdx.x;
  __shared__ float row_s[EMBD];
  int tid = threadIdx.x;
  float ss = 0.f;
  for (int d = tid; d < EMBD; d += 128) {
    float x = embv[(size_t)r * EMBD + d];
    row_s[d] = x;
    ss += x * x;
  }
  float tot = blockReduceSum(ss);
  float inv = 1.f / fmaxf(sqrtf(tot), 1e-12f);
  if (tid < NCLS) {
    float acc = 0.f;
    for (int d = 0; d < DD; ++d) acc += row_s[d] * rn[(size_t)tid * EMBD + d];
    out[(size_t)r * NCLS + tid] = acc * inv;
  }
}

extern "C" void kernel_launch(void* const* d_in, const int* in_sizes, int n_in,
                              void* d_out, int out_size, void* d_ws, size_t ws_size,
                              hipStream_t stream) {
  const float* seq   = (const float*)d_in[0];
  const float* att   = (const float*)d_in[1];
  const int*   midx  = (const int*)d_in[2];
  const unsigned char* mask = (const unsigned char*)d_in[3];
  const int*   pairs = (const int*)d_in[4];
  const float* headW = (const float*)d_in[5];
  const float* headb = (const float*)d_in[6];
  const float* tailW = (const float*)d_in[7];
  const float* tailb = (const float*)d_in[8];
  const float* bilW  = (const float*)d_in[9];
  const float* bilb  = (const float*)d_in[10];
  const float* remb  = (const float*)d_in[11];
  const float* reW   = (const float*)d_in[12];
  const float* reb   = (const float*)d_in[13];
  float* out = (float*)d_out;

  float* w = (float*)d_ws;
  float* e_emb = w;  w += (size_t)NN * EE * DD;
  float* cntv  = w;  w += NN * EE;
  int*   vbuf  = (int*)w; w += NN * EE;
  float* e_att = w;  w += (size_t)NN * EE * HH * CC;
  float* ht    = w;  w += (size_t)NN * PP * CC;
  float* xh    = w;  w += (size_t)NP * K2D;
  float* xt    = w;  w += (size_t)NP * K2D;
  float* hs2   = w;  w += (size_t)NP * EMBD;
  float* ts2   = w;  w += (size_t)NP * EMBD;
  float* embv  = w;  w += (size_t)NP * EMBD;
  float* rn    = w;  w += (size_t)NCLS * EMBD;

  k_entity<<<NN * EE, 256, 0, stream>>>(seq, midx, mask, e_emb, cntv, vbuf);
  k_eatt<<<NN * EE * HH, 256, 0, stream>>>(att, midx, cntv, vbuf, e_att);
  k_ht<<<NN * PP, 256, 0, stream>>>(e_att, pairs, ht);
  k_rs<<<NN * PP, 256, 0, stream>>>(ht, seq, e_emb, pairs, xh, xt);
  dim3 g5(NP / 64, EMBD / 64);
  k_gemm_tanh<<<g5, 256, 0, stream>>>(xh, headW, headb, hs2);
  k_gemm_tanh<<<g5, 256, 0, stream>>>(xt, tailW, tailb, ts2);
  dim3 g6(NP / 64, EMBD / 64);
  k_bilinear<<<g6, 256, 0, stream>>>(hs2, ts2, bilW, bilb, embv);
  k_rel<<<NCLS, 256, 0, stream>>>(remb, reW, reb, rn);
  k_logits<<<NP, 128, 0, stream>>>(embv, rn, out);
}

// Round 2
// 905.600 us; speedup vs baseline: 4.9134x; 4.9134x over previous
//
#include <hip/hip_runtime.h>
#include <hip/hip_bf16.h>
#include <math.h>

#define NN 4
#define CC 1024
#define DD 768
#define HH 12
#define EE 32
#define MM 4
#define PP 256
#define EMBD 768
#define BSZ 64
#define NCLS 97
#define NP (NN*PP)      // 1024
#define K2D (2*DD)      // 1536
#define OFFS 1

#define KSPLIT 6
#define GPB 2           // k-groups per bilinear block (12 / KSPLIT)

typedef __attribute__((ext_vector_type(4))) float f32x4;
typedef __attribute__((ext_vector_type(4))) int   i32x4;
typedef __attribute__((ext_vector_type(8))) __bf16 bf16x8;

union U8 { bf16x8 bv; i32x4 iv; unsigned u[4]; };

__device__ __forceinline__ unsigned short f2bfu(float x) {
  __hip_bfloat16 h = __float2bfloat16(x);
  unsigned short s;
  __builtin_memcpy(&s, &h, 2);
  return s;
}
__device__ __forceinline__ float bfu2f(unsigned short s) {
  return __uint_as_float(((unsigned)s) << 16);
}

__device__ __forceinline__ float blockReduceSum(float v) {
  #pragma unroll
  for (int off = 32; off > 0; off >>= 1) v += __shfl_down(v, off, 64);
  __shared__ float red_s[8];
  int wid = threadIdx.x >> 6, lane = threadIdx.x & 63;
  int nw = (blockDim.x + 63) >> 6;
  if (lane == 0) red_s[wid] = v;
  __syncthreads();
  if (threadIdx.x == 0) {
    float s = 0.f;
    for (int i = 0; i < nw; ++i) s += red_s[i];
    red_s[0] = s;
  }
  __syncthreads();
  float r = red_s[0];
  __syncthreads();
  return r;
}

// K1: e_emb (logsumexp over valid mentions) + cnt + valid bitmask
__global__ __launch_bounds__(256) void k_entity(const float* __restrict__ seq,
                                                const int* __restrict__ midx,
                                                const unsigned char* __restrict__ mask,
                                                float* __restrict__ e_emb,
                                                float* __restrict__ cntv,
                                                int* __restrict__ vbuf) {
  int ne = blockIdx.x;
  int n = ne / EE;
  __shared__ int pos_s[MM];
  __shared__ int val_s[MM];
  if (threadIdx.x == 0) {
    // detect mask storage: 1-byte bool => every int32 word of first 512B is odd
    const int* wm = (const int*)mask;
    int allodd = 1;
    for (int i = 0; i < NN * EE; ++i) {
      if ((wm[i] & 1) == 0) { allodd = 0; break; }
    }
    int vb = 0, cnt = 0;
    for (int m = 0; m < MM; ++m) {
      int idx = midx[ne * MM + m];
      int p = idx + OFFS; if (p > CC - 1) p = CC - 1;
      pos_s[m] = p;
      int v = allodd ? (mask[ne * MM + m] != 0) : (wm[ne * MM + m] != 0);
      val_s[m] = v;
      if (v) { vb |= (1 << m); cnt++; }
    }
    cntv[ne] = (float)cnt;
    vbuf[ne] = vb;
  }
  __syncthreads();
  const float* sb = seq + (size_t)n * CC * DD;
  for (int d = threadIdx.x; d < DD; d += 256) {
    float x[MM];
    float mx = -1e30f;
    #pragma unroll
    for (int m = 0; m < MM; ++m) {
      x[m] = val_s[m] ? sb[(size_t)pos_s[m] * DD + d] : 0.f;
      if (val_s[m]) mx = fmaxf(mx, x[m]);
    }
    float s = 0.f;
    #pragma unroll
    for (int m = 0; m < MM; ++m) {
      if (val_s[m]) s += expf(x[m] - mx);
    }
    e_emb[(size_t)ne * DD + d] = mx + logf(s);
  }
}

// K2: e_att[n][e][h][c] = (1/cnt) * sum_valid att[n,h,pos,c]
__global__ __launch_bounds__(256) void k_eatt(const float* __restrict__ att,
                                              const int* __restrict__ midx,
                                              const float* __restrict__ cntv,
                                              const int* __restrict__ vbuf,
                                              float* __restrict__ e_att) {
  int b = blockIdx.x;
  int n = b / (EE * HH);
  int rem = b % (EE * HH);
  int e = rem / HH, h = rem % HH;
  int ne = n * EE + e;
  __shared__ int pos_s[MM];
  __shared__ int nv_s;
  __shared__ float inv_s;
  if (threadIdx.x == 0) {
    int vb = vbuf[ne];
    int cp = 0;
    for (int m = 0; m < MM; ++m) {
      if (vb & (1 << m)) {
        int p = midx[ne * MM + m] + OFFS; if (p > CC - 1) p = CC - 1;
        pos_s[cp++] = p;
      }
    }
    nv_s = cp;
    inv_s = 1.f / cntv[ne];
  }
  __syncthreads();
  const float* ab = att + ((size_t)n * HH + h) * CC * CC;
  float* ob = e_att + ((size_t)ne * HH + h) * CC;
  int nv = nv_s;
  float inv = inv_s;
  for (int c = threadIdx.x; c < CC; c += 256) {
    float s = 0.f;
    for (int m = 0; m < nv; ++m) s += ab[(size_t)pos_s[m] * CC + c];
    ob[c] = s * inv;
  }
}

// K3: ht[n][p][c] = normalize_c( mean_h(h_att * t_att) )
__global__ __launch_bounds__(256) void k_ht(const float* __restrict__ e_att,
                                            const int* __restrict__ pairs,
                                            float* __restrict__ ht) {
  int np = blockIdx.x;
  int n = np >> 8;  // P=256
  int tid = threadIdx.x;
  int ph = pairs[np * 2], pt = pairs[np * 2 + 1];
  const float* ha = e_att + ((size_t)(n * EE + ph)) * HH * CC;
  const float* ta = e_att + ((size_t)(n * EE + pt)) * HH * CC;
  float v[4];
  float lsum = 0.f;
  #pragma unroll
  for (int i = 0; i < 4; ++i) {
    int c = tid + i * 256;
    float s = 0.f;
    #pragma unroll
    for (int h = 0; h < HH; ++h) s += ha[(size_t)h * CC + c] * ta[(size_t)h * CC + c];
    s *= (1.f / HH);
    v[i] = s;
    lsum += s;
  }
  float tot = blockReduceSum(lsum);
  float inv = 1.f / (tot + 1e-5f);
  #pragma unroll
  for (int i = 0; i < 4; ++i) ht[(size_t)np * CC + tid + i * 256] = v[i] * inv;
}

// K4: rs = ht @ seq; build X_h = [hs | rs], X_t = [ts | rs]
__global__ __launch_bounds__(256) void k_rs(const float* __restrict__ ht,
                                            const float* __restrict__ seq,
                                            const float* __restrict__ e_emb,
                                            const int* __restrict__ pairs,
                                            float* __restrict__ xh,
                                            float* __restrict__ xt) {
  int np = blockIdx.x;
  int n = np >> 8;
  int tid = threadIdx.x;
  __shared__ float hts[CC];
  for (int c = tid; c < CC; c += 256) hts[c] = ht[(size_t)np * CC + c];
  __syncthreads();
  int ph = pairs[np * 2], pt = pairs[np * 2 + 1];
  const float* he = e_emb + (size_t)(n * EE + ph) * DD;
  const float* te = e_emb + (size_t)(n * EE + pt) * DD;
  const float* sb = seq + (size_t)n * CC * DD;
  float acc0 = 0.f, acc1 = 0.f, acc2 = 0.f;
  for (int c = 0; c < CC; ++c) {
    float hv = hts[c];
    const float* s = sb + (size_t)c * DD + tid;
    acc0 += hv * s[0];
    acc1 += hv * s[256];
    acc2 += hv * s[512];
  }
  size_t base = (size_t)np * K2D;
  xh[base + DD + tid]       = acc0; xt[base + DD + tid]       = acc0;
  xh[base + DD + tid + 256] = acc1; xt[base + DD + tid + 256] = acc1;
  xh[base + DD + tid + 512] = acc2; xt[base + DD + tid + 512] = acc2;
  xh[base + tid]       = he[tid];       xt[base + tid]       = te[tid];
  xh[base + tid + 256] = he[tid + 256]; xt[base + tid + 256] = te[tid + 256];
  xh[base + tid + 512] = he[tid + 512]; xt[base + tid + 512] = te[tid + 512];
}

// K5: outb = bf16(tanh(A(1024x1536) @ W(1536x768) + b))
__global__ __launch_bounds__(256) void k_gemm_tanh(const float* __restrict__ A,
                                                   const float* __restrict__ W,
                                                   const float* __restrict__ bias,
                                                   unsigned short* __restrict__ outb) {
  __shared__ float As[64][17];
  __shared__ float Wts[16][64];
  int r0 = blockIdx.x * 64, o0 = blockIdx.y * 64;
  int tid = threadIdx.x;
  int tx = tid & 15, ty = tid >> 4;
  float acc[4][4] = {};
  for (int k0 = 0; k0 < K2D; k0 += 16) {
    __syncthreads();
    #pragma unroll
    for (int i = tid; i < 64 * 16; i += 256) {
      int rr = i >> 4, kk = i & 15;
      As[rr][kk] = A[(size_t)(r0 + rr) * K2D + k0 + kk];
    }
    #pragma unroll
    for (int i = tid; i < 16 * 64; i += 256) {
      int kk = i >> 6, oo = i & 63;
      Wts[kk][oo] = W[(size_t)(k0 + kk) * EMBD + o0 + oo];
    }
    __syncthreads();
    #pragma unroll
    for (int kk = 0; kk < 16; ++kk) {
      float a[4];
      #pragma unroll
      for (int rr = 0; rr < 4; ++rr) a[rr] = As[ty * 4 + rr][kk];
      float4 wv = *(const float4*)&Wts[kk][tx * 4];
      float wb[4] = {wv.x, wv.y, wv.z, wv.w};
      #pragma unroll
      for (int rr = 0; rr < 4; ++rr)
        #pragma unroll
        for (int oo = 0; oo < 4; ++oo)
          acc[rr][oo] += a[rr] * wb[oo];
    }
  }
  #pragma unroll
  for (int rr = 0; rr < 4; ++rr) {
    int r = r0 + ty * 4 + rr;
    #pragma unroll
    for (int oo = 0; oo < 4; ++oo) {
      int o = o0 + tx * 4 + oo;
      outb[(size_t)r * EMBD + o] = f2bfu(tanhf(acc[rr][oo] + bias[o]));
    }
  }
}

// K6: group bilinear via MFMA. emb_partial[z][r][o] = sum over k-groups z*GPB..+GPB
//   of sum_{i,j} b1[r,k,i] b2[r,k,j] W[k,i,j,o].
// A-matrix generated on the fly: A[r, (k,i,j)] = b1[r,k,i]*b2[r,k,j].
// Tiles: BM=128 rows, BN=128 cols, 4 waves (2x2), each wave 64x64.
#define WSTR 72
__global__ __launch_bounds__(256, 2) void k_bil_mfma(
    const unsigned short* __restrict__ hsb,
    const unsigned short* __restrict__ tsb,
    const float* __restrict__ bilW,
    float* __restrict__ part) {
  __shared__ __align__(16) unsigned short b1s[128][WSTR];
  __shared__ __align__(16) unsigned short b2s[128][WSTR];
  __shared__ __align__(16) unsigned short Ws[128][WSTR];   // [o][j]
  const int tid = threadIdx.x;
  const int lane = tid & 63;
  const int wid = tid >> 6;
  const int wr = wid >> 1, wc = wid & 1;
  const int r0 = blockIdx.x * 128;
  const int o0 = blockIdx.y * 128;
  const int z = blockIdx.z;
  const int l15 = lane & 15, lg = lane >> 4;

  f32x4 acc[4][4];
  #pragma unroll
  for (int a = 0; a < 4; ++a)
    #pragma unroll
    for (int b = 0; b < 4; ++b) acc[a][b] = (f32x4){0.f, 0.f, 0.f, 0.f};

  float b2f[4][2][8];
  f32x4 wreg[4][2];

  const int jp = tid >> 3;   // 0..31 -> j rows 2jp, 2jp+1
  const int ob = tid & 7;    // o-quad sub-base

  // prefetch W tile for it=0
  {
    const float* Wb = bilW + ((size_t)(z * GPB) * 4096) * EMBD + o0;
    #pragma unroll
    for (int u = 0; u < 4; ++u) {
      wreg[u][0] = *(const f32x4*)&Wb[(size_t)(2 * jp) * EMBD + 4 * (ob + 8 * u)];
      wreg[u][1] = *(const f32x4*)&Wb[(size_t)(2 * jp + 1) * EMBD + 4 * (ob + 8 * u)];
    }
  }

  const int nit = GPB * 64;
  for (int it = 0; it < nit; ++it) {
    const int i = it & 63;
    if (i == 0) {
      const int g = z * GPB + (it >> 6);
      __syncthreads();
      for (int uu = tid; uu < 128 * 8; uu += 256) {
        int rr = uu >> 3, ch = uu & 7;
        *(i32x4*)&b1s[rr][ch * 8] = *(const i32x4*)&hsb[(size_t)(r0 + rr) * EMBD + g * 64 + ch * 8];
        *(i32x4*)&b2s[rr][ch * 8] = *(const i32x4*)&tsb[(size_t)(r0 + rr) * EMBD + g * 64 + ch * 8];
      }
      __syncthreads();
      #pragma unroll
      for (int mt = 0; mt < 4; ++mt)
        #pragma unroll
        for (int ks = 0; ks < 2; ++ks) {
          U8 t;
          t.iv = *(const i32x4*)&b2s[wr * 64 + mt * 16 + l15][ks * 32 + lg * 8];
          const unsigned short* sp = (const unsigned short*)&t.iv;
          #pragma unroll
          for (int e = 0; e < 8; ++e) b2f[mt][ks][e] = bfu2f(sp[e]);
        }
    }
    __syncthreads();   // Ws free (previous readers done)
    // write prefetched W tile (fp32 regs -> bf16 LDS, transposed to [o][j])
    #pragma unroll
    for (int u = 0; u < 4; ++u) {
      const float* f0 = (const float*)&wreg[u][0];
      const float* f1 = (const float*)&wreg[u][1];
      #pragma unroll
      for (int c = 0; c < 4; ++c) {
        unsigned pk = (unsigned)f2bfu(f0[c]) | ((unsigned)f2bfu(f1[c]) << 16);
        *(unsigned*)&Ws[4 * (ob + 8 * u) + c][2 * jp] = pk;
      }
    }
    // prefetch next W tile
    if (it + 1 < nit) {
      const int g2 = z * GPB + ((it + 1) >> 6), i2 = (it + 1) & 63;
      const float* Wb = bilW + ((size_t)g2 * 4096 + (size_t)i2 * 64) * EMBD + o0;
      #pragma unroll
      for (int u = 0; u < 4; ++u) {
        wreg[u][0] = *(const f32x4*)&Wb[(size_t)(2 * jp) * EMBD + 4 * (ob + 8 * u)];
        wreg[u][1] = *(const f32x4*)&Wb[(size_t)(2 * jp + 1) * EMBD + 4 * (ob + 8 * u)];
      }
    }
    __syncthreads();   // Ws ready
    // b1 scalars for this i
    float b1f[4];
    #pragma unroll
    for (int mt = 0; mt < 4; ++mt)
      b1f[mt] = bfu2f(b1s[wr * 64 + mt * 16 + l15][i]);
    // A-fragments: a = bf16(b1 * b2)
    U8 afr[4][2];
    #pragma unroll
    for (int mt = 0; mt < 4; ++mt)
      #pragma unroll
      for (int ks = 0; ks < 2; ++ks)
        #pragma unroll
        for (int p = 0; p < 4; ++p) {
          unsigned lo = f2bfu(b1f[mt] * b2f[mt][ks][2 * p]);
          unsigned hi = f2bfu(b1f[mt] * b2f[mt][ks][2 * p + 1]);
          afr[mt][ks].u[p] = lo | (hi << 16);
        }
    // MFMA
    #pragma unroll
    for (int nt = 0; nt < 4; ++nt)
      #pragma unroll
      for (int ks = 0; ks < 2; ++ks) {
        U8 bfr;
        bfr.iv = *(const i32x4*)&Ws[wc * 64 + nt * 16 + l15][ks * 32 + lg * 8];
        #pragma unroll
        for (int mt = 0; mt < 4; ++mt)
          acc[mt][nt] = __builtin_amdgcn_mfma_f32_16x16x32_bf16(afr[mt][ks].bv, bfr.bv, acc[mt][nt], 0, 0, 0);
      }
  }
  // store partials: D row = (lg*4 + v), col = l15 within each 16x16 tile
  float* pb = part + (size_t)z * NP * EMBD;
  #pragma unroll
  for (int mt = 0; mt < 4; ++mt)
    #pragma unroll
    for (int v = 0; v < 4; ++v) {
      int row = r0 + wr * 64 + mt * 16 + lg * 4 + v;
      #pragma unroll
      for (int nt = 0; nt < 4; ++nt) {
        int col = o0 + wc * 64 + nt * 16 + l15;
        pb[(size_t)row * EMBD + col] = acc[mt][nt][v];
      }
    }
}

// K6b: reduce partials + bias -> embv
__global__ __launch_bounds__(256) void k_bred(const float* __restrict__ part,
                                              const float* __restrict__ bilb,
                                              float* __restrict__ embv) {
  int idx = blockIdx.x * 256 + threadIdx.x;   // < NP*EMBD
  int o = idx - (idx / EMBD) * EMBD;
  float s = bilb[o];
  #pragma unroll
  for (int zz = 0; zz < KSPLIT; ++zz) s += part[(size_t)zz * NP * EMBD + idx];
  embv[idx] = s;
}

// K7: rn = l2norm(r_emb_table @ re_W + re_b)
__global__ __launch_bounds__(256) void k_rel(const float* __restrict__ remb,
                                             const float* __restrict__ reW,
                                             const float* __restrict__ reb,
                                             float* __restrict__ rn) {
  int c = blockIdx.x;
  __shared__ float row_s[DD];
  int tid = threadIdx.x;
  for (int d = tid; d < DD; d += 256) row_s[d] = remb[(size_t)c * DD + d];
  __syncthreads();
  float v[3];
  float ss = 0.f;
  #pragma unroll
  for (int i = 0; i < 3; ++i) {
    int j = tid + i * 256;
    float acc = reb[j];
    for (int d = 0; d < DD; ++d) acc += row_s[d] * reW[(size_t)d * EMBD + j];
    v[i] = acc;
    ss += acc * acc;
  }
  float tot = blockReduceSum(ss);
  float scale = 1.f / fmaxf(sqrtf(tot), 1e-12f);
  #pragma unroll
  for (int i = 0; i < 3; ++i) rn[(size_t)c * EMBD + tid + i * 256] = v[i] * scale;
}

// K8: logits[r,c] = l2norm(emb[r]) . rn[c]
__global__ __launch_bounds__(128) void k_logits(const float* __restrict__ embv,
                                                const float* __restrict__ rn,
                                                float* __restrict__ out) {
  int r = blockIdx.x;
  __shared__ float row_s[EMBD];
  int tid = threadIdx.x;
  float ss = 0.f;
  for (int d = tid; d < EMBD; d += 128) {
    float x = embv[(size_t)r * EMBD + d];
    row_s[d] = x;
    ss += x * x;
  }
  float tot = blockReduceSum(ss);
  float inv = 1.f / fmaxf(sqrtf(tot), 1e-12f);
  if (tid < NCLS) {
    float acc = 0.f;
    for (int d = 0; d < DD; ++d) acc += row_s[d] * rn[(size_t)tid * EMBD + d];
    out[(size_t)r * NCLS + tid] = acc * inv;
  }
}

extern "C" void kernel_launch(void* const* d_in, const int* in_sizes, int n_in,
                              void* d_out, int out_size, void* d_ws, size_t ws_size,
                              hipStream_t stream) {
  const float* seq   = (const float*)d_in[0];
  const float* att   = (const float*)d_in[1];
  const int*   midx  = (const int*)d_in[2];
  const unsigned char* mask = (const unsigned char*)d_in[3];
  const int*   pairs = (const int*)d_in[4];
  const float* headW = (const float*)d_in[5];
  const float* headb = (const float*)d_in[6];
  const float* tailW = (const float*)d_in[7];
  const float* tailb = (const float*)d_in[8];
  const float* bilW  = (const float*)d_in[9];
  const float* bilb  = (const float*)d_in[10];
  const float* remb  = (const float*)d_in[11];
  const float* reW   = (const float*)d_in[12];
  const float* reb   = (const float*)d_in[13];
  float* out = (float*)d_out;

  float* w = (float*)d_ws;
  float* e_emb = w;  w += (size_t)NN * EE * DD;
  float* cntv  = w;  w += NN * EE;
  int*   vbuf  = (int*)w; w += NN * EE;
  float* e_att = w;  w += (size_t)NN * EE * HH * CC;     // 1,572,864 f
  float* ht    = w;  w += (size_t)NN * PP * CC;          // 1,048,576 f
  float* xh    = w;  w += (size_t)NP * K2D;              // 1,572,864 f
  float* xt    = w;  w += (size_t)NP * K2D;              // 1,572,864 f
  float* embv  = w;  w += (size_t)NP * EMBD;
  float* rn    = w;  w += (size_t)NCLS * EMBD;
  unsigned short* hsb = (unsigned short*)w;              // bf16 [1024][768]
  w += (size_t)NP * EMBD / 2;
  unsigned short* tsb = (unsigned short*)w;
  w += (size_t)NP * EMBD / 2;
  // partials alias e_att..xt (all dead before k_bil_mfma runs):
  // need KSPLIT * NP * EMBD = 6 * 786432 floats = 18.9 MB <= 23.07 MB region
  float* part = e_att;

  k_entity<<<NN * EE, 256, 0, stream>>>(seq, midx, mask, e_emb, cntv, vbuf);
  k_eatt<<<NN * EE * HH, 256, 0, stream>>>(att, midx, cntv, vbuf, e_att);
  k_ht<<<NN * PP, 256, 0, stream>>>(e_att, pairs, ht);
  k_rs<<<NN * PP, 256, 0, stream>>>(ht, seq, e_emb, pairs, xh, xt);
  dim3 g5(NP / 64, EMBD / 64);
  k_gemm_tanh<<<g5, 256, 0, stream>>>(xh, headW, headb, hsb);
  k_gemm_tanh<<<g5, 256, 0, stream>>>(xt, tailW, tailb, tsb);
  dim3 g6(NP / 128, EMBD / 128, KSPLIT);
  k_bil_mfma<<<g6, 256, 0, stream>>>(hsb, tsb, bilW, part);
  k_bred<<<(NP * EMBD) / 256, 256, 0, stream>>>(part, bilb, embv);
  k_rel<<<NCLS, 256, 0, stream>>>(remb, reW, reb, rn);
  k_logits<<<NP, 128, 0, stream>>>(embv, rn, out);
}

// Round 3
// 456.651 us; speedup vs baseline: 9.7440x; 1.9831x over previous
//
#include <hip/hip_runtime.h>
#include <hip/hip_bf16.h>
#include <math.h>

#define NN 4
#define CC 1024
#define DD 768
#define HH 12
#define EE 32
#define MM 4
#define PP 256
#define EMBD 768
#define BSZ 64
#define NCLS 97
#define NP (NN*PP)      // 1024
#define K2D (2*DD)      // 1536
#define OFFS 1

#define KSPLIT 6
#define GPB 2           // k-groups per bilinear block (12 / KSPLIT)

typedef __attribute__((ext_vector_type(4))) float f32x4;
typedef __attribute__((ext_vector_type(4))) int   i32x4;
typedef __attribute__((ext_vector_type(8))) __bf16 bf16x8;

union U8 { bf16x8 bv; i32x4 iv; unsigned u[4]; };

__device__ __forceinline__ unsigned short f2bfu(float x) {
  __hip_bfloat16 h = __float2bfloat16(x);
  unsigned short s;
  __builtin_memcpy(&s, &h, 2);
  return s;
}
__device__ __forceinline__ float bfu2f(unsigned short s) {
  return __uint_as_float(((unsigned)s) << 16);
}

__device__ __forceinline__ float blockReduceSum(float v) {
  #pragma unroll
  for (int off = 32; off > 0; off >>= 1) v += __shfl_down(v, off, 64);
  __shared__ float red_s[8];
  int wid = threadIdx.x >> 6, lane = threadIdx.x & 63;
  int nw = (blockDim.x + 63) >> 6;
  if (lane == 0) red_s[wid] = v;
  __syncthreads();
  if (threadIdx.x == 0) {
    float s = 0.f;
    for (int i = 0; i < nw; ++i) s += red_s[i];
    red_s[0] = s;
  }
  __syncthreads();
  float r = red_s[0];
  __syncthreads();
  return r;
}

// K1: e_emb (logsumexp over valid mentions) + cnt + valid bitmask
__global__ __launch_bounds__(256) void k_entity(const float* __restrict__ seq,
                                                const int* __restrict__ midx,
                                                const unsigned char* __restrict__ mask,
                                                float* __restrict__ e_emb,
                                                float* __restrict__ cntv,
                                                int* __restrict__ vbuf) {
  int ne = blockIdx.x;
  int n = ne / EE;
  __shared__ int pos_s[MM];
  __shared__ int val_s[MM];
  if (threadIdx.x == 0) {
    const int* wm = (const int*)mask;
    int allodd = 1;
    for (int i = 0; i < NN * EE; ++i) {
      if ((wm[i] & 1) == 0) { allodd = 0; break; }
    }
    int vb = 0, cnt = 0;
    for (int m = 0; m < MM; ++m) {
      int idx = midx[ne * MM + m];
      int p = idx + OFFS; if (p > CC - 1) p = CC - 1;
      pos_s[m] = p;
      int v = allodd ? (mask[ne * MM + m] != 0) : (wm[ne * MM + m] != 0);
      val_s[m] = v;
      if (v) { vb |= (1 << m); cnt++; }
    }
    cntv[ne] = (float)cnt;
    vbuf[ne] = vb;
  }
  __syncthreads();
  const float* sb = seq + (size_t)n * CC * DD;
  for (int d = threadIdx.x; d < DD; d += 256) {
    float x[MM];
    float mx = -1e30f;
    #pragma unroll
    for (int m = 0; m < MM; ++m) {
      x[m] = val_s[m] ? sb[(size_t)pos_s[m] * DD + d] : 0.f;
      if (val_s[m]) mx = fmaxf(mx, x[m]);
    }
    float s = 0.f;
    #pragma unroll
    for (int m = 0; m < MM; ++m) {
      if (val_s[m]) s += expf(x[m] - mx);
    }
    e_emb[(size_t)ne * DD + d] = mx + logf(s);
  }
}

// K2: e_att[n][e][h][c] = (1/cnt) * sum_valid att[n,h,pos,c]
__global__ __launch_bounds__(256) void k_eatt(const float* __restrict__ att,
                                              const int* __restrict__ midx,
                                              const float* __restrict__ cntv,
                                              const int* __restrict__ vbuf,
                                              float* __restrict__ e_att) {
  int b = blockIdx.x;
  int n = b / (EE * HH);
  int rem = b % (EE * HH);
  int e = rem / HH, h = rem % HH;
  int ne = n * EE + e;
  __shared__ int pos_s[MM];
  __shared__ int nv_s;
  __shared__ float inv_s;
  if (threadIdx.x == 0) {
    int vb = vbuf[ne];
    int cp = 0;
    for (int m = 0; m < MM; ++m) {
      if (vb & (1 << m)) {
        int p = midx[ne * MM + m] + OFFS; if (p > CC - 1) p = CC - 1;
        pos_s[cp++] = p;
      }
    }
    nv_s = cp;
    inv_s = 1.f / cntv[ne];
  }
  __syncthreads();
  const float* ab = att + ((size_t)n * HH + h) * CC * CC;
  float* ob = e_att + ((size_t)ne * HH + h) * CC;
  int nv = nv_s;
  float inv = inv_s;
  for (int c = threadIdx.x; c < CC; c += 256) {
    float s = 0.f;
    for (int m = 0; m < nv; ++m) s += ab[(size_t)pos_s[m] * CC + c];
    ob[c] = s * inv;
  }
}

// K3: ht[n][p][c] = normalize_c( mean_h(h_att * t_att) )
__global__ __launch_bounds__(256) void k_ht(const float* __restrict__ e_att,
                                            const int* __restrict__ pairs,
                                            float* __restrict__ ht) {
  int np = blockIdx.x;
  int n = np >> 8;  // P=256
  int tid = threadIdx.x;
  int ph = pairs[np * 2], pt = pairs[np * 2 + 1];
  const float* ha = e_att + ((size_t)(n * EE + ph)) * HH * CC;
  const float* ta = e_att + ((size_t)(n * EE + pt)) * HH * CC;
  float v[4];
  float lsum = 0.f;
  #pragma unroll
  for (int i = 0; i < 4; ++i) {
    int c = tid + i * 256;
    float s = 0.f;
    #pragma unroll
    for (int h = 0; h < HH; ++h) s += ha[(size_t)h * CC + c] * ta[(size_t)h * CC + c];
    s *= (1.f / HH);
    v[i] = s;
    lsum += s;
  }
  float tot = blockReduceSum(lsum);
  float inv = 1.f / (tot + 1e-5f);
  #pragma unroll
  for (int i = 0; i < 4; ++i) ht[(size_t)np * CC + tid + i * 256] = v[i] * inv;
}

// K4a: fill hs/ts halves of X from e_emb gathers
__global__ __launch_bounds__(256) void k_fill(const float* __restrict__ e_emb,
                                              const int* __restrict__ pairs,
                                              float* __restrict__ xh,
                                              float* __restrict__ xt) {
  int np = blockIdx.x;
  int n = np >> 8;
  int ph = pairs[np * 2], pt = pairs[np * 2 + 1];
  const float* he = e_emb + (size_t)(n * EE + ph) * DD;
  const float* te = e_emb + (size_t)(n * EE + pt) * DD;
  #pragma unroll
  for (int i = 0; i < 3; ++i) {
    int d = threadIdx.x + i * 256;
    xh[(size_t)np * K2D + d] = he[d];
    xt[(size_t)np * K2D + d] = te[d];
  }
}

#define WSTR 72

// K4b: rs = ht @ seq via MFMA (per doc), writes fp32 into xh/xt cols 768..1535
__global__ __launch_bounds__(256, 2) void k_rs_mfma(const float* __restrict__ ht,
                                                    const float* __restrict__ seq,
                                                    float* __restrict__ xh,
                                                    float* __restrict__ xt) {
  __shared__ __align__(16) unsigned short As[128][WSTR];
  __shared__ __align__(16) unsigned short Bs[128][WSTR];   // [n][k]
  const int tid = threadIdx.x;
  const int lane = tid & 63, wid = tid >> 6;
  const int wr = wid >> 1, wc = wid & 1;
  const int l15 = lane & 15, lg = lane >> 4;
  const int n = blockIdx.z;
  const int r0 = blockIdx.x * 128;          // row within doc (0 or 128)
  const int o0 = blockIdx.y * 128;          // output col in [0,768)
  const int jp = tid >> 3, ob = tid & 7;
  const float* Ab = ht + ((size_t)n * PP + r0) * CC;
  const float* Bb = seq + (size_t)n * CC * DD;

  f32x4 acc[4][4];
  #pragma unroll
  for (int a = 0; a < 4; ++a)
    #pragma unroll
    for (int b = 0; b < 4; ++b) acc[a][b] = (f32x4){0.f, 0.f, 0.f, 0.f};

  for (int k0 = 0; k0 < CC; k0 += 64) {
    __syncthreads();
    // stage A (ht rows, fp32 -> bf16)
    #pragma unroll
    for (int uu = 0; uu < 4; ++uu) {
      int idx = tid + uu * 256;
      int row = idx >> 3, ch = idx & 7;
      const float* ap = Ab + (size_t)row * CC + k0 + ch * 8;
      f32x4 v0 = *(const f32x4*)ap;
      f32x4 v1 = *(const f32x4*)(ap + 4);
      const float* f0 = (const float*)&v0;
      const float* f1 = (const float*)&v1;
      i32x4 hv;
      #pragma unroll
      for (int p = 0; p < 2; ++p)
        hv[p] = (unsigned)f2bfu(f0[2 * p]) | ((unsigned)f2bfu(f0[2 * p + 1]) << 16);
      #pragma unroll
      for (int p = 0; p < 2; ++p)
        hv[2 + p] = (unsigned)f2bfu(f1[2 * p]) | ((unsigned)f2bfu(f1[2 * p + 1]) << 16);
      *(i32x4*)&As[row][ch * 8] = hv;
    }
    // stage B transposed (seq [k][d] fp32 -> Bs[d][k] bf16), pack k-pairs
    #pragma unroll
    for (int u = 0; u < 4; ++u) {
      f32x4 w0 = *(const f32x4*)&Bb[(size_t)(k0 + 2 * jp) * DD + o0 + 4 * (ob + 8 * u)];
      f32x4 w1 = *(const f32x4*)&Bb[(size_t)(k0 + 2 * jp + 1) * DD + o0 + 4 * (ob + 8 * u)];
      const float* f0 = (const float*)&w0;
      const float* f1 = (const float*)&w1;
      #pragma unroll
      for (int c = 0; c < 4; ++c) {
        unsigned pk = (unsigned)f2bfu(f0[c]) | ((unsigned)f2bfu(f1[c]) << 16);
        *(unsigned*)&Bs[4 * (ob + 8 * u) + c][2 * jp] = pk;
      }
    }
    __syncthreads();
    #pragma unroll
    for (int kc = 0; kc < 2; ++kc) {
      U8 bfr[4];
      #pragma unroll
      for (int nt = 0; nt < 4; ++nt)
        bfr[nt].iv = *(const i32x4*)&Bs[wc * 64 + nt * 16 + l15][kc * 32 + lg * 8];
      #pragma unroll
      for (int mt = 0; mt < 4; ++mt) {
        U8 af;
        af.iv = *(const i32x4*)&As[wr * 64 + mt * 16 + l15][kc * 32 + lg * 8];
        #pragma unroll
        for (int nt = 0; nt < 4; ++nt)
          acc[mt][nt] = __builtin_amdgcn_mfma_f32_16x16x32_bf16(af.bv, bfr[nt].bv, acc[mt][nt], 0, 0, 0);
      }
    }
  }
  #pragma unroll
  for (int mt = 0; mt < 4; ++mt)
    #pragma unroll
    for (int v = 0; v < 4; ++v) {
      int np = n * PP + r0 + wr * 64 + mt * 16 + lg * 4 + v;
      #pragma unroll
      for (int nt = 0; nt < 4; ++nt) {
        int col = o0 + wc * 64 + nt * 16 + l15;
        float val = acc[mt][nt][v];
        xh[(size_t)np * K2D + DD + col] = val;
        xt[(size_t)np * K2D + DD + col] = val;
      }
    }
}

// K5: outb = bf16(tanh(A @ W + b)), A fp32 [1024][1536] hi/lo-split to bf16
__global__ __launch_bounds__(256, 2) void k_tanh_mfma(const float* __restrict__ xh,
                                                      const float* __restrict__ xt,
                                                      const float* __restrict__ headW,
                                                      const float* __restrict__ tailW,
                                                      const float* __restrict__ headb,
                                                      const float* __restrict__ tailb,
                                                      unsigned short* __restrict__ hsb,
                                                      unsigned short* __restrict__ tsb) {
  __shared__ __align__(16) unsigned short Ahi[128][WSTR];
  __shared__ __align__(16) unsigned short Alo[128][WSTR];
  __shared__ __align__(16) unsigned short Ws[128][WSTR];   // [o][k]
  const int z = blockIdx.z;
  const float* A = z ? xt : xh;
  const float* W = z ? tailW : headW;
  const float* bias = z ? tailb : headb;
  unsigned short* outb = z ? tsb : hsb;
  const int tid = threadIdx.x;
  const int lane = tid & 63, wid = tid >> 6;
  const int wr = wid >> 1, wc = wid & 1;
  const int l15 = lane & 15, lg = lane >> 4;
  const int r0 = blockIdx.x * 128, o0 = blockIdx.y * 128;
  const int jp = tid >> 3, ob = tid & 7;

  f32x4 acc[4][4];
  #pragma unroll
  for (int a = 0; a < 4; ++a)
    #pragma unroll
    for (int b = 0; b < 4; ++b) acc[a][b] = (f32x4){0.f, 0.f, 0.f, 0.f};

  for (int k0 = 0; k0 < K2D; k0 += 64) {
    __syncthreads();
    // stage A hi/lo
    #pragma unroll
    for (int uu = 0; uu < 4; ++uu) {
      int idx = tid + uu * 256;
      int row = idx >> 3, ch = idx & 7;
      const float* ap = A + (size_t)(r0 + row) * K2D + k0 + ch * 8;
      f32x4 v0 = *(const f32x4*)ap;
      f32x4 v1 = *(const f32x4*)(ap + 4);
      const float* fv0 = (const float*)&v0;
      const float* fv1 = (const float*)&v1;
      float fv[8] = {fv0[0], fv0[1], fv0[2], fv0[3], fv1[0], fv1[1], fv1[2], fv1[3]};
      unsigned short h[8], l[8];
      #pragma unroll
      for (int e = 0; e < 8; ++e) {
        h[e] = f2bfu(fv[e]);
        l[e] = f2bfu(fv[e] - bfu2f(h[e]));
      }
      i32x4 hv, lv;
      #pragma unroll
      for (int p = 0; p < 4; ++p) {
        hv[p] = (unsigned)h[2 * p] | ((unsigned)h[2 * p + 1] << 16);
        lv[p] = (unsigned)l[2 * p] | ((unsigned)l[2 * p + 1] << 16);
      }
      *(i32x4*)&Ahi[row][ch * 8] = hv;
      *(i32x4*)&Alo[row][ch * 8] = lv;
    }
    // stage W transposed
    #pragma unroll
    for (int u = 0; u < 4; ++u) {
      f32x4 w0 = *(const f32x4*)&W[(size_t)(k0 + 2 * jp) * EMBD + o0 + 4 * (ob + 8 * u)];
      f32x4 w1 = *(const f32x4*)&W[(size_t)(k0 + 2 * jp + 1) * EMBD + o0 + 4 * (ob + 8 * u)];
      const float* f0 = (const float*)&w0;
      const float* f1 = (const float*)&w1;
      #pragma unroll
      for (int c = 0; c < 4; ++c) {
        unsigned pk = (unsigned)f2bfu(f0[c]) | ((unsigned)f2bfu(f1[c]) << 16);
        *(unsigned*)&Ws[4 * (ob + 8 * u) + c][2 * jp] = pk;
      }
    }
    __syncthreads();
    #pragma unroll
    for (int kc = 0; kc < 2; ++kc) {
      U8 bfr[4];
      #pragma unroll
      for (int nt = 0; nt < 4; ++nt)
        bfr[nt].iv = *(const i32x4*)&Ws[wc * 64 + nt * 16 + l15][kc * 32 + lg * 8];
      #pragma unroll
      for (int mt = 0; mt < 4; ++mt) {
        U8 ah, al;
        ah.iv = *(const i32x4*)&Ahi[wr * 64 + mt * 16 + l15][kc * 32 + lg * 8];
        al.iv = *(const i32x4*)&Alo[wr * 64 + mt * 16 + l15][kc * 32 + lg * 8];
        #pragma unroll
        for (int nt = 0; nt < 4; ++nt) {
          acc[mt][nt] = __builtin_amdgcn_mfma_f32_16x16x32_bf16(ah.bv, bfr[nt].bv, acc[mt][nt], 0, 0, 0);
          acc[mt][nt] = __builtin_amdgcn_mfma_f32_16x16x32_bf16(al.bv, bfr[nt].bv, acc[mt][nt], 0, 0, 0);
        }
      }
    }
  }
  float bv[4];
  #pragma unroll
  for (int nt = 0; nt < 4; ++nt) bv[nt] = bias[o0 + wc * 64 + nt * 16 + l15];
  #pragma unroll
  for (int mt = 0; mt < 4; ++mt)
    #pragma unroll
    for (int v = 0; v < 4; ++v) {
      int row = r0 + wr * 64 + mt * 16 + lg * 4 + v;
      #pragma unroll
      for (int nt = 0; nt < 4; ++nt) {
        int col = o0 + wc * 64 + nt * 16 + l15;
        outb[(size_t)row * EMBD + col] = f2bfu(tanhf(acc[mt][nt][v] + bv[nt]));
      }
    }
}

// K6: group bilinear via MFMA (unchanged from round 1)
__global__ __launch_bounds__(256, 2) void k_bil_mfma(
    const unsigned short* __restrict__ hsb,
    const unsigned short* __restrict__ tsb,
    const float* __restrict__ bilW,
    float* __restrict__ part) {
  __shared__ __align__(16) unsigned short b1s[128][WSTR];
  __shared__ __align__(16) unsigned short b2s[128][WSTR];
  __shared__ __align__(16) unsigned short Ws[128][WSTR];   // [o][j]
  const int tid = threadIdx.x;
  const int lane = tid & 63;
  const int wid = tid >> 6;
  const int wr = wid >> 1, wc = wid & 1;
  const int r0 = blockIdx.x * 128;
  const int o0 = blockIdx.y * 128;
  const int z = blockIdx.z;
  const int l15 = lane & 15, lg = lane >> 4;

  f32x4 acc[4][4];
  #pragma unroll
  for (int a = 0; a < 4; ++a)
    #pragma unroll
    for (int b = 0; b < 4; ++b) acc[a][b] = (f32x4){0.f, 0.f, 0.f, 0.f};

  float b2f[4][2][8];
  f32x4 wreg[4][2];

  const int jp = tid >> 3;   // 0..31 -> j rows 2jp, 2jp+1
  const int ob = tid & 7;    // o-quad sub-base

  {
    const float* Wb = bilW + ((size_t)(z * GPB) * 4096) * EMBD + o0;
    #pragma unroll
    for (int u = 0; u < 4; ++u) {
      wreg[u][0] = *(const f32x4*)&Wb[(size_t)(2 * jp) * EMBD + 4 * (ob + 8 * u)];
      wreg[u][1] = *(const f32x4*)&Wb[(size_t)(2 * jp + 1) * EMBD + 4 * (ob + 8 * u)];
    }
  }

  const int nit = GPB * 64;
  for (int it = 0; it < nit; ++it) {
    const int i = it & 63;
    if (i == 0) {
      const int g = z * GPB + (it >> 6);
      __syncthreads();
      for (int uu = tid; uu < 128 * 8; uu += 256) {
        int rr = uu >> 3, ch = uu & 7;
        *(i32x4*)&b1s[rr][ch * 8] = *(const i32x4*)&hsb[(size_t)(r0 + rr) * EMBD + g * 64 + ch * 8];
        *(i32x4*)&b2s[rr][ch * 8] = *(const i32x4*)&tsb[(size_t)(r0 + rr) * EMBD + g * 64 + ch * 8];
      }
      __syncthreads();
      #pragma unroll
      for (int mt = 0; mt < 4; ++mt)
        #pragma unroll
        for (int ks = 0; ks < 2; ++ks) {
          U8 t;
          t.iv = *(const i32x4*)&b2s[wr * 64 + mt * 16 + l15][ks * 32 + lg * 8];
          const unsigned short* sp = (const unsigned short*)&t.iv;
          #pragma unroll
          for (int e = 0; e < 8; ++e) b2f[mt][ks][e] = bfu2f(sp[e]);
        }
    }
    __syncthreads();
    #pragma unroll
    for (int u = 0; u < 4; ++u) {
      const float* f0 = (const float*)&wreg[u][0];
      const float* f1 = (const float*)&wreg[u][1];
      #pragma unroll
      for (int c = 0; c < 4; ++c) {
        unsigned pk = (unsigned)f2bfu(f0[c]) | ((unsigned)f2bfu(f1[c]) << 16);
        *(unsigned*)&Ws[4 * (ob + 8 * u) + c][2 * jp] = pk;
      }
    }
    if (it + 1 < nit) {
      const int g2 = z * GPB + ((it + 1) >> 6), i2 = (it + 1) & 63;
      const float* Wb = bilW + ((size_t)g2 * 4096 + (size_t)i2 * 64) * EMBD + o0;
      #pragma unroll
      for (int u = 0; u < 4; ++u) {
        wreg[u][0] = *(const f32x4*)&Wb[(size_t)(2 * jp) * EMBD + 4 * (ob + 8 * u)];
        wreg[u][1] = *(const f32x4*)&Wb[(size_t)(2 * jp + 1) * EMBD + 4 * (ob + 8 * u)];
      }
    }
    __syncthreads();
    float b1f[4];
    #pragma unroll
    for (int mt = 0; mt < 4; ++mt)
      b1f[mt] = bfu2f(b1s[wr * 64 + mt * 16 + l15][i]);
    U8 afr[4][2];
    #pragma unroll
    for (int mt = 0; mt < 4; ++mt)
      #pragma unroll
      for (int ks = 0; ks < 2; ++ks)
        #pragma unroll
        for (int p = 0; p < 4; ++p) {
          unsigned lo = f2bfu(b1f[mt] * b2f[mt][ks][2 * p]);
          unsigned hi = f2bfu(b1f[mt] * b2f[mt][ks][2 * p + 1]);
          afr[mt][ks].u[p] = lo | (hi << 16);
        }
    #pragma unroll
    for (int nt = 0; nt < 4; ++nt)
      #pragma unroll
      for (int ks = 0; ks < 2; ++ks) {
        U8 bfr;
        bfr.iv = *(const i32x4*)&Ws[wc * 64 + nt * 16 + l15][ks * 32 + lg * 8];
        #pragma unroll
        for (int mt = 0; mt < 4; ++mt)
          acc[mt][nt] = __builtin_amdgcn_mfma_f32_16x16x32_bf16(afr[mt][ks].bv, bfr.bv, acc[mt][nt], 0, 0, 0);
      }
  }
  float* pb = part + (size_t)z * NP * EMBD;
  #pragma unroll
  for (int mt = 0; mt < 4; ++mt)
    #pragma unroll
    for (int v = 0; v < 4; ++v) {
      int row = r0 + wr * 64 + mt * 16 + lg * 4 + v;
      #pragma unroll
      for (int nt = 0; nt < 4; ++nt) {
        int col = o0 + wc * 64 + nt * 16 + l15;
        pb[(size_t)row * EMBD + col] = acc[mt][nt][v];
      }
    }
}

// K6b: reduce partials + bias -> embv
__global__ __launch_bounds__(256) void k_bred(const float* __restrict__ part,
                                              const float* __restrict__ bilb,
                                              float* __restrict__ embv) {
  int idx = blockIdx.x * 256 + threadIdx.x;
  int o = idx - (idx / EMBD) * EMBD;
  float s = bilb[o];
  #pragma unroll
  for (int zz = 0; zz < KSPLIT; ++zz) s += part[(size_t)zz * NP * EMBD + idx];
  embv[idx] = s;
}

// K7: rn = l2norm(r_emb_table @ re_W + re_b)
__global__ __launch_bounds__(256) void k_rel(const float* __restrict__ remb,
                                             const float* __restrict__ reW,
                                             const float* __restrict__ reb,
                                             float* __restrict__ rn) {
  int c = blockIdx.x;
  __shared__ float row_s[DD];
  int tid = threadIdx.x;
  for (int d = tid; d < DD; d += 256) row_s[d] = remb[(size_t)c * DD + d];
  __syncthreads();
  float v[3];
  float ss = 0.f;
  #pragma unroll
  for (int i = 0; i < 3; ++i) {
    int j = tid + i * 256;
    float acc = reb[j];
    for (int d = 0; d < DD; ++d) acc += row_s[d] * reW[(size_t)d * EMBD + j];
    v[i] = acc;
    ss += acc * acc;
  }
  float tot = blockReduceSum(ss);
  float scale = 1.f / fmaxf(sqrtf(tot), 1e-12f);
  #pragma unroll
  for (int i = 0; i < 3; ++i) rn[(size_t)c * EMBD + tid + i * 256] = v[i] * scale;
}

// K8: logits[r,c] = l2norm(emb[r]) . rn[c]
__global__ __launch_bounds__(128) void k_logits(const float* __restrict__ embv,
                                                const float* __restrict__ rn,
                                                float* __restrict__ out) {
  int r = blockIdx.x;
  __shared__ float row_s[EMBD];
  int tid = threadIdx.x;
  float ss = 0.f;
  for (int d = tid; d < EMBD; d += 128) {
    float x = embv[(size_t)r * EMBD + d];
    row_s[d] = x;
    ss += x * x;
  }
  float tot = blockReduceSum(ss);
  float inv = 1.f / fmaxf(sqrtf(tot), 1e-12f);
  if (tid < NCLS) {
    float acc = 0.f;
    for (int d = 0; d < DD; ++d) acc += row_s[d] * rn[(size_t)tid * EMBD + d];
    out[(size_t)r * NCLS + tid] = acc * inv;
  }
}

extern "C" void kernel_launch(void* const* d_in, const int* in_sizes, int n_in,
                              void* d_out, int out_size, void* d_ws, size_t ws_size,
                              hipStream_t stream) {
  const float* seq   = (const float*)d_in[0];
  const float* att   = (const float*)d_in[1];
  const int*   midx  = (const int*)d_in[2];
  const unsigned char* mask = (const unsigned char*)d_in[3];
  const int*   pairs = (const int*)d_in[4];
  const float* headW = (const float*)d_in[5];
  const float* headb = (const float*)d_in[6];
  const float* tailW = (const float*)d_in[7];
  const float* tailb = (const float*)d_in[8];
  const float* bilW  = (const float*)d_in[9];
  const float* bilb  = (const float*)d_in[10];
  const float* remb  = (const float*)d_in[11];
  const float* reW   = (const float*)d_in[12];
  const float* reb   = (const float*)d_in[13];
  float* out = (float*)d_out;

  float* w = (float*)d_ws;
  float* e_emb = w;  w += (size_t)NN * EE * DD;
  float* cntv  = w;  w += NN * EE;
  int*   vbuf  = (int*)w; w += NN * EE;
  float* e_att = w;  w += (size_t)NN * EE * HH * CC;     // 1,572,864 f
  float* ht    = w;  w += (size_t)NN * PP * CC;          // 1,048,576 f
  float* xh    = w;  w += (size_t)NP * K2D;              // 1,572,864 f
  float* xt    = w;  w += (size_t)NP * K2D;              // 1,572,864 f
  float* embv  = w;  w += (size_t)NP * EMBD;
  float* rn    = w;  w += (size_t)NCLS * EMBD;
  unsigned short* hsb = (unsigned short*)w;              // bf16 [1024][768]
  w += (size_t)NP * EMBD / 2;
  unsigned short* tsb = (unsigned short*)w;
  w += (size_t)NP * EMBD / 2;
  // partials alias e_att..xt (dead before k_bil_mfma):
  float* part = e_att;

  k_entity<<<NN * EE, 256, 0, stream>>>(seq, midx, mask, e_emb, cntv, vbuf);
  k_eatt<<<NN * EE * HH, 256, 0, stream>>>(att, midx, cntv, vbuf, e_att);
  k_ht<<<NN * PP, 256, 0, stream>>>(e_att, pairs, ht);
  k_fill<<<NP, 256, 0, stream>>>(e_emb, pairs, xh, xt);
  dim3 g4(2, 6, NN);
  k_rs_mfma<<<g4, 256, 0, stream>>>(ht, seq, xh, xt);
  dim3 g5(NP / 128, EMBD / 128, 2);
  k_tanh_mfma<<<g5, 256, 0, stream>>>(xh, xt, headW, tailW, headb, tailb, hsb, tsb);
  dim3 g6(NP / 128, EMBD / 128, KSPLIT);
  k_bil_mfma<<<g6, 256, 0, stream>>>(hsb, tsb, bilW, part);
  k_bred<<<(NP * EMBD) / 256, 256, 0, stream>>>(part, bilb, embv);
  k_rel<<<NCLS, 256, 0, stream>>>(remb, reW, reb, rn);
  k_logits<<<NP, 128, 0, stream>>>(embv, rn, out);
}

// Round 4
// 373.498 us; speedup vs baseline: 11.9133x; 1.2226x over previous
//
#include <hip/hip_runtime.h>
#include <hip/hip_bf16.h>
#include <math.h>

#define NN 4
#define CC 1024
#define DD 768
#define HH 12
#define EE 32
#define MM 4
#define PP 256
#define EMBD 768
#define BSZ 64
#define NCLS 97
#define NP (NN*PP)      // 1024
#define K2D (2*DD)      // 1536
#define OFFS 1

typedef __attribute__((ext_vector_type(4))) float f32x4;
typedef __attribute__((ext_vector_type(4))) int   i32x4;
typedef __attribute__((ext_vector_type(8))) __bf16 bf16x8;

union U8 { bf16x8 bv; i32x4 iv; unsigned u[4]; };

__device__ __forceinline__ unsigned short f2bfu(float x) {
  __hip_bfloat16 h = __float2bfloat16(x);
  unsigned short s;
  __builtin_memcpy(&s, &h, 2);
  return s;
}
__device__ __forceinline__ float bfu2f(unsigned short s) {
  return __uint_as_float(((unsigned)s) << 16);
}

__device__ __forceinline__ float blockReduceSum(float v) {
  #pragma unroll
  for (int off = 32; off > 0; off >>= 1) v += __shfl_down(v, off, 64);
  __shared__ float red_s[8];
  int wid = threadIdx.x >> 6, lane = threadIdx.x & 63;
  int nw = (blockDim.x + 63) >> 6;
  if (lane == 0) red_s[wid] = v;
  __syncthreads();
  if (threadIdx.x == 0) {
    float s = 0.f;
    for (int i = 0; i < nw; ++i) s += red_s[i];
    red_s[0] = s;
  }
  __syncthreads();
  float r = red_s[0];
  __syncthreads();
  return r;
}

// K1: e_emb (logsumexp over valid mentions) + cnt + valid bitmask
__global__ __launch_bounds__(256) void k_entity(const float* __restrict__ seq,
                                                const int* __restrict__ midx,
                                                const unsigned char* __restrict__ mask,
                                                float* __restrict__ e_emb,
                                                float* __restrict__ cntv,
                                                int* __restrict__ vbuf) {
  int ne = blockIdx.x;
  int n = ne / EE;
  __shared__ int pos_s[MM];
  __shared__ int val_s[MM];
  if (threadIdx.x == 0) {
    const int* wm = (const int*)mask;
    int allodd = 1;
    for (int i = 0; i < NN * EE; ++i) {
      if ((wm[i] & 1) == 0) { allodd = 0; break; }
    }
    int vb = 0, cnt = 0;
    for (int m = 0; m < MM; ++m) {
      int idx = midx[ne * MM + m];
      int p = idx + OFFS; if (p > CC - 1) p = CC - 1;
      pos_s[m] = p;
      int v = allodd ? (mask[ne * MM + m] != 0) : (wm[ne * MM + m] != 0);
      val_s[m] = v;
      if (v) { vb |= (1 << m); cnt++; }
    }
    cntv[ne] = (float)cnt;
    vbuf[ne] = vb;
  }
  __syncthreads();
  const float* sb = seq + (size_t)n * CC * DD;
  for (int d = threadIdx.x; d < DD; d += 256) {
    float x[MM];
    float mx = -1e30f;
    #pragma unroll
    for (int m = 0; m < MM; ++m) {
      x[m] = val_s[m] ? sb[(size_t)pos_s[m] * DD + d] : 0.f;
      if (val_s[m]) mx = fmaxf(mx, x[m]);
    }
    float s = 0.f;
    #pragma unroll
    for (int m = 0; m < MM; ++m) {
      if (val_s[m]) s += expf(x[m] - mx);
    }
    e_emb[(size_t)ne * DD + d] = mx + logf(s);
  }
}

// K2: e_att[n][e][h][c] = (1/cnt) * sum_valid att[n,h,pos,c]
__global__ __launch_bounds__(256) void k_eatt(const float* __restrict__ att,
                                              const int* __restrict__ midx,
                                              const float* __restrict__ cntv,
                                              const int* __restrict__ vbuf,
                                              float* __restrict__ e_att) {
  int b = blockIdx.x;
  int n = b / (EE * HH);
  int rem = b % (EE * HH);
  int e = rem / HH, h = rem % HH;
  int ne = n * EE + e;
  __shared__ int pos_s[MM];
  __shared__ int nv_s;
  __shared__ float inv_s;
  if (threadIdx.x == 0) {
    int vb = vbuf[ne];
    int cp = 0;
    for (int m = 0; m < MM; ++m) {
      if (vb & (1 << m)) {
        int p = midx[ne * MM + m] + OFFS; if (p > CC - 1) p = CC - 1;
        pos_s[cp++] = p;
      }
    }
    nv_s = cp;
    inv_s = 1.f / cntv[ne];
  }
  __syncthreads();
  const float* ab = att + ((size_t)n * HH + h) * CC * CC;
  float* ob = e_att + ((size_t)ne * HH + h) * CC;
  int nv = nv_s;
  float inv = inv_s;
  for (int c = threadIdx.x; c < CC; c += 256) {
    float s = 0.f;
    for (int m = 0; m < nv; ++m) s += ab[(size_t)pos_s[m] * CC + c];
    ob[c] = s * inv;
  }
}

// K3: ht[n][p][c] = normalize_c( mean_h(h_att * t_att) )
__global__ __launch_bounds__(256) void k_ht(const float* __restrict__ e_att,
                                            const int* __restrict__ pairs,
                                            float* __restrict__ ht) {
  int np = blockIdx.x;
  int n = np >> 8;  // P=256
  int tid = threadIdx.x;
  int ph = pairs[np * 2], pt = pairs[np * 2 + 1];
  const float* ha = e_att + ((size_t)(n * EE + ph)) * HH * CC;
  const float* ta = e_att + ((size_t)(n * EE + pt)) * HH * CC;
  float v[4];
  float lsum = 0.f;
  #pragma unroll
  for (int i = 0; i < 4; ++i) {
    int c = tid + i * 256;
    float s = 0.f;
    #pragma unroll
    for (int h = 0; h < HH; ++h) s += ha[(size_t)h * CC + c] * ta[(size_t)h * CC + c];
    s *= (1.f / HH);
    v[i] = s;
    lsum += s;
  }
  float tot = blockReduceSum(lsum);
  float inv = 1.f / (tot + 1e-5f);
  #pragma unroll
  for (int i = 0; i < 4; ++i) ht[(size_t)np * CC + tid + i * 256] = v[i] * inv;
}

// K4a: fill hs/ts halves of X from e_emb gathers
__global__ __launch_bounds__(256) void k_fill(const float* __restrict__ e_emb,
                                              const int* __restrict__ pairs,
                                              float* __restrict__ xh,
                                              float* __restrict__ xt) {
  int np = blockIdx.x;
  int n = np >> 8;
  int ph = pairs[np * 2], pt = pairs[np * 2 + 1];
  const float* he = e_emb + (size_t)(n * EE + ph) * DD;
  const float* te = e_emb + (size_t)(n * EE + pt) * DD;
  #pragma unroll
  for (int i = 0; i < 3; ++i) {
    int d = threadIdx.x + i * 256;
    xh[(size_t)np * K2D + d] = he[d];
    xt[(size_t)np * K2D + d] = te[d];
  }
}

#define WSTR 72

// K4b: rs = ht @ seq via MFMA. BM=64, BN=64, 4 waves (2x2), wave tile 32x32.
__global__ __launch_bounds__(256, 2) void k_rs_mfma(const float* __restrict__ ht,
                                                    const float* __restrict__ seq,
                                                    float* __restrict__ xh,
                                                    float* __restrict__ xt) {
  __shared__ __align__(16) unsigned short As[64][WSTR];
  __shared__ __align__(16) unsigned short Bs[64][WSTR];   // [o][k]
  const int tid = threadIdx.x;
  const int lane = tid & 63, wid = tid >> 6;
  const int wr = wid >> 1, wc = wid & 1;
  const int l15 = lane & 15, lg = lane >> 4;
  const int n = blockIdx.z;
  const int r0 = blockIdx.x * 64;           // row within doc
  const int o0 = blockIdx.y * 64;           // output col in [0,768)
  const int jp = tid >> 3, ob = tid & 7;
  const float* Ab = ht + ((size_t)n * PP + r0) * CC;
  const float* Bb = seq + (size_t)n * CC * DD;

  f32x4 acc[2][2];
  #pragma unroll
  for (int a = 0; a < 2; ++a)
    #pragma unroll
    for (int b = 0; b < 2; ++b) acc[a][b] = (f32x4){0.f, 0.f, 0.f, 0.f};

  for (int k0 = 0; k0 < CC; k0 += 64) {
    __syncthreads();
    // stage A (ht rows 64 x 64k, fp32 -> bf16)
    #pragma unroll
    for (int uu = 0; uu < 2; ++uu) {
      int idx = tid + uu * 256;
      int row = idx >> 3, ch = idx & 7;
      const float* ap = Ab + (size_t)row * CC + k0 + ch * 8;
      f32x4 v0 = *(const f32x4*)ap;
      f32x4 v1 = *(const f32x4*)(ap + 4);
      const float* f0 = (const float*)&v0;
      const float* f1 = (const float*)&v1;
      i32x4 hv;
      #pragma unroll
      for (int p = 0; p < 2; ++p)
        hv[p] = (unsigned)f2bfu(f0[2 * p]) | ((unsigned)f2bfu(f0[2 * p + 1]) << 16);
      #pragma unroll
      for (int p = 0; p < 2; ++p)
        hv[2 + p] = (unsigned)f2bfu(f1[2 * p]) | ((unsigned)f2bfu(f1[2 * p + 1]) << 16);
      *(i32x4*)&As[row][ch * 8] = hv;
    }
    // stage B transposed (seq [k][d] fp32 -> Bs[d][k] bf16), pack k-pairs
    #pragma unroll
    for (int u = 0; u < 2; ++u) {
      f32x4 w0 = *(const f32x4*)&Bb[(size_t)(k0 + 2 * jp) * DD + o0 + 4 * (ob + 8 * u)];
      f32x4 w1 = *(const f32x4*)&Bb[(size_t)(k0 + 2 * jp + 1) * DD + o0 + 4 * (ob + 8 * u)];
      const float* f0 = (const float*)&w0;
      const float* f1 = (const float*)&w1;
      #pragma unroll
      for (int c = 0; c < 4; ++c) {
        unsigned pk = (unsigned)f2bfu(f0[c]) | ((unsigned)f2bfu(f1[c]) << 16);
        *(unsigned*)&Bs[4 * (ob + 8 * u) + c][2 * jp] = pk;
      }
    }
    __syncthreads();
    #pragma unroll
    for (int kc = 0; kc < 2; ++kc) {
      U8 bfr[2];
      #pragma unroll
      for (int nt = 0; nt < 2; ++nt)
        bfr[nt].iv = *(const i32x4*)&Bs[wc * 32 + nt * 16 + l15][kc * 32 + lg * 8];
      #pragma unroll
      for (int mt = 0; mt < 2; ++mt) {
        U8 af;
        af.iv = *(const i32x4*)&As[wr * 32 + mt * 16 + l15][kc * 32 + lg * 8];
        #pragma unroll
        for (int nt = 0; nt < 2; ++nt)
          acc[mt][nt] = __builtin_amdgcn_mfma_f32_16x16x32_bf16(af.bv, bfr[nt].bv, acc[mt][nt], 0, 0, 0);
      }
    }
  }
  #pragma unroll
  for (int mt = 0; mt < 2; ++mt)
    #pragma unroll
    for (int v = 0; v < 4; ++v) {
      int np = n * PP + r0 + wr * 32 + mt * 16 + lg * 4 + v;
      #pragma unroll
      for (int nt = 0; nt < 2; ++nt) {
        int col = o0 + wc * 32 + nt * 16 + l15;
        float val = acc[mt][nt][v];
        xh[(size_t)np * K2D + DD + col] = val;
        xt[(size_t)np * K2D + DD + col] = val;
      }
    }
}

// K5: outb = bf16(tanh(A @ W + b)), A fp32 hi/lo-split. BM=64, BN=128.
__global__ __launch_bounds__(256, 2) void k_tanh_mfma(const float* __restrict__ xh,
                                                      const float* __restrict__ xt,
                                                      const float* __restrict__ headW,
                                                      const float* __restrict__ tailW,
                                                      const float* __restrict__ headb,
                                                      const float* __restrict__ tailb,
                                                      unsigned short* __restrict__ hsb,
                                                      unsigned short* __restrict__ tsb) {
  __shared__ __align__(16) unsigned short Ahi[64][WSTR];
  __shared__ __align__(16) unsigned short Alo[64][WSTR];
  __shared__ __align__(16) unsigned short Ws[128][WSTR];   // [o][k]
  const int z = blockIdx.z;
  const float* A = z ? xt : xh;
  const float* W = z ? tailW : headW;
  const float* bias = z ? tailb : headb;
  unsigned short* outb = z ? tsb : hsb;
  const int tid = threadIdx.x;
  const int lane = tid & 63, wid = tid >> 6;
  const int wr = wid >> 1, wc = wid & 1;
  const int l15 = lane & 15, lg = lane >> 4;
  const int r0 = blockIdx.x * 64, o0 = blockIdx.y * 128;
  const int jp = tid >> 3, ob = tid & 7;

  f32x4 acc[2][4];
  #pragma unroll
  for (int a = 0; a < 2; ++a)
    #pragma unroll
    for (int b = 0; b < 4; ++b) acc[a][b] = (f32x4){0.f, 0.f, 0.f, 0.f};

  for (int k0 = 0; k0 < K2D; k0 += 64) {
    __syncthreads();
    // stage A hi/lo (64 rows x 64 k)
    #pragma unroll
    for (int uu = 0; uu < 2; ++uu) {
      int idx = tid + uu * 256;
      int row = idx >> 3, ch = idx & 7;
      const float* ap = A + (size_t)(r0 + row) * K2D + k0 + ch * 8;
      f32x4 v0 = *(const f32x4*)ap;
      f32x4 v1 = *(const f32x4*)(ap + 4);
      const float* fv0 = (const float*)&v0;
      const float* fv1 = (const float*)&v1;
      float fv[8] = {fv0[0], fv0[1], fv0[2], fv0[3], fv1[0], fv1[1], fv1[2], fv1[3]};
      unsigned short h[8], l[8];
      #pragma unroll
      for (int e = 0; e < 8; ++e) {
        h[e] = f2bfu(fv[e]);
        l[e] = f2bfu(fv[e] - bfu2f(h[e]));
      }
      i32x4 hv, lv;
      #pragma unroll
      for (int p = 0; p < 4; ++p) {
        hv[p] = (unsigned)h[2 * p] | ((unsigned)h[2 * p + 1] << 16);
        lv[p] = (unsigned)l[2 * p] | ((unsigned)l[2 * p + 1] << 16);
      }
      *(i32x4*)&Ahi[row][ch * 8] = hv;
      *(i32x4*)&Alo[row][ch * 8] = lv;
    }
    // stage W transposed (64k x 128o)
    #pragma unroll
    for (int u = 0; u < 4; ++u) {
      f32x4 w0 = *(const f32x4*)&W[(size_t)(k0 + 2 * jp) * EMBD + o0 + 4 * (ob + 8 * u)];
      f32x4 w1 = *(const f32x4*)&W[(size_t)(k0 + 2 * jp + 1) * EMBD + o0 + 4 * (ob + 8 * u)];
      const float* f0 = (const float*)&w0;
      const float* f1 = (const float*)&w1;
      #pragma unroll
      for (int c = 0; c < 4; ++c) {
        unsigned pk = (unsigned)f2bfu(f0[c]) | ((unsigned)f2bfu(f1[c]) << 16);
        *(unsigned*)&Ws[4 * (ob + 8 * u) + c][2 * jp] = pk;
      }
    }
    __syncthreads();
    #pragma unroll
    for (int kc = 0; kc < 2; ++kc) {
      U8 bfr[4];
      #pragma unroll
      for (int nt = 0; nt < 4; ++nt)
        bfr[nt].iv = *(const i32x4*)&Ws[wc * 64 + nt * 16 + l15][kc * 32 + lg * 8];
      #pragma unroll
      for (int mt = 0; mt < 2; ++mt) {
        U8 ah, al;
        ah.iv = *(const i32x4*)&Ahi[wr * 32 + mt * 16 + l15][kc * 32 + lg * 8];
        al.iv = *(const i32x4*)&Alo[wr * 32 + mt * 16 + l15][kc * 32 + lg * 8];
        #pragma unroll
        for (int nt = 0; nt < 4; ++nt) {
          acc[mt][nt] = __builtin_amdgcn_mfma_f32_16x16x32_bf16(ah.bv, bfr[nt].bv, acc[mt][nt], 0, 0, 0);
          acc[mt][nt] = __builtin_amdgcn_mfma_f32_16x16x32_bf16(al.bv, bfr[nt].bv, acc[mt][nt], 0, 0, 0);
        }
      }
    }
  }
  float bv[4];
  #pragma unroll
  for (int nt = 0; nt < 4; ++nt) bv[nt] = bias[o0 + wc * 64 + nt * 16 + l15];
  #pragma unroll
  for (int mt = 0; mt < 2; ++mt)
    #pragma unroll
    for (int v = 0; v < 4; ++v) {
      int row = r0 + wr * 32 + mt * 16 + lg * 4 + v;
      #pragma unroll
      for (int nt = 0; nt < 4; ++nt) {
        int col = o0 + wc * 64 + nt * 16 + l15;
        outb[(size_t)row * EMBD + col] = f2bfu(tanhf(acc[mt][nt][v] + bv[nt]));
      }
    }
}

// K6: group bilinear via MFMA. BM=128, BN=128, 2x2 waves, wave 64x64.
// 1-D grid with XCD-aware decode: all 8 row-blocks of one (oy,z) W-slice
// land on the same XCD (slice W = gpb*2MB fits its 4MB L2).
// b2 frags from global (L2-hot), b1 in LDS, W double-buffered (1 barrier/it).
__global__ __launch_bounds__(256, 2) void k_bil_mfma(
    const unsigned short* __restrict__ hsb,
    const unsigned short* __restrict__ tsb,
    const float* __restrict__ bilW,
    float* __restrict__ part,
    int nslice, int gpb) {
  __shared__ __align__(16) unsigned short b1s[128][WSTR];
  __shared__ __align__(16) unsigned short Ws[2][128][WSTR];   // [o][j], dbuf
  const int d = blockIdx.x;
  const int xcd = d & 7;
  const int q = d >> 3;
  const int r = q & 7;
  const int sl = q >> 3;
  const int s = xcd + 8 * sl;
  if (s >= nslice) return;
  const int oy = s % 6;
  const int z = s / 6;
  const int r0 = r * 128;
  const int o0 = oy * 128;

  const int tid = threadIdx.x;
  const int lane = tid & 63, wid = tid >> 6;
  const int wr = wid >> 1, wc = wid & 1;
  const int l15 = lane & 15, lg = lane >> 4;
  const int jp = tid >> 3, ob = tid & 7;

  f32x4 acc[4][4];
  #pragma unroll
  for (int a = 0; a < 4; ++a)
    #pragma unroll
    for (int b = 0; b < 4; ++b) acc[a][b] = (f32x4){0.f, 0.f, 0.f, 0.f};

  for (int gi = 0; gi < gpb; ++gi) {
    const int g = z * gpb + gi;
    __syncthreads();   // previous group's readers done
    // stage b1 (hsb) rows r0..r0+127, cols g*64..+63
    #pragma unroll
    for (int uu = 0; uu < 4; ++uu) {
      int idx = tid + uu * 256;
      int row = idx >> 3, ch = idx & 7;
      *(i32x4*)&b1s[row][ch * 8] =
          *(const i32x4*)&hsb[(size_t)(r0 + row) * EMBD + g * 64 + ch * 8];
    }
    // preload b2 fragments from global (f32)
    float b2f[4][2][8];
    #pragma unroll
    for (int mt = 0; mt < 4; ++mt)
      #pragma unroll
      for (int ks = 0; ks < 2; ++ks) {
        i32x4 t = *(const i32x4*)&tsb[(size_t)(r0 + wr * 64 + mt * 16 + l15) * EMBD + g * 64 + ks * 32 + lg * 8];
        const unsigned short* sp = (const unsigned short*)&t;
        #pragma unroll
        for (int e = 0; e < 8; ++e) b2f[mt][ks][e] = bfu2f(sp[e]);
      }
    // prefetch W tile for it=0
    const float* WbBase = bilW + (size_t)g * 4096 * EMBD + o0;
    f32x4 wreg[4][2];
    #pragma unroll
    for (int u = 0; u < 4; ++u) {
      wreg[u][0] = *(const f32x4*)&WbBase[(size_t)(2 * jp) * EMBD + 4 * (ob + 8 * u)];
      wreg[u][1] = *(const f32x4*)&WbBase[(size_t)(2 * jp + 1) * EMBD + 4 * (ob + 8 * u)];
    }

    for (int it = 0; it < 64; ++it) {
      const int buf = it & 1;
      // write prefetched W tile to LDS (fp32 -> bf16, transposed to [o][j])
      #pragma unroll
      for (int u = 0; u < 4; ++u) {
        const float* f0 = (const float*)&wreg[u][0];
        const float* f1 = (const float*)&wreg[u][1];
        #pragma unroll
        for (int c = 0; c < 4; ++c) {
          unsigned pk = (unsigned)f2bfu(f0[c]) | ((unsigned)f2bfu(f1[c]) << 16);
          *(unsigned*)&Ws[buf][4 * (ob + 8 * u) + c][2 * jp] = pk;
        }
      }
      // prefetch next W tile
      if (it + 1 < 64) {
        const float* Wb = WbBase + (size_t)(it + 1) * 64 * EMBD;
        #pragma unroll
        for (int u = 0; u < 4; ++u) {
          wreg[u][0] = *(const f32x4*)&Wb[(size_t)(2 * jp) * EMBD + 4 * (ob + 8 * u)];
          wreg[u][1] = *(const f32x4*)&Wb[(size_t)(2 * jp + 1) * EMBD + 4 * (ob + 8 * u)];
        }
      }
      __syncthreads();   // Ws[buf] ready (also covers b1s stage on it=0)
      // b1 scalars for this i
      float b1f[4];
      #pragma unroll
      for (int mt = 0; mt < 4; ++mt)
        b1f[mt] = bfu2f(b1s[wr * 64 + mt * 16 + l15][it]);
      // A-fragments: a = bf16(b1 * b2)
      U8 afr[4][2];
      #pragma unroll
      for (int mt = 0; mt < 4; ++mt)
        #pragma unroll
        for (int ks = 0; ks < 2; ++ks)
          #pragma unroll
          for (int p = 0; p < 4; ++p) {
            unsigned lo = f2bfu(b1f[mt] * b2f[mt][ks][2 * p]);
            unsigned hi = f2bfu(b1f[mt] * b2f[mt][ks][2 * p + 1]);
            afr[mt][ks].u[p] = lo | (hi << 16);
          }
      // MFMA
      #pragma unroll
      for (int nt = 0; nt < 4; ++nt)
        #pragma unroll
        for (int ks = 0; ks < 2; ++ks) {
          U8 bfr;
          bfr.iv = *(const i32x4*)&Ws[buf][wc * 64 + nt * 16 + l15][ks * 32 + lg * 8];
          #pragma unroll
          for (int mt = 0; mt < 4; ++mt)
            acc[mt][nt] = __builtin_amdgcn_mfma_f32_16x16x32_bf16(afr[mt][ks].bv, bfr.bv, acc[mt][nt], 0, 0, 0);
        }
    }
  }
  float* pb = part + (size_t)z * NP * EMBD;
  #pragma unroll
  for (int mt = 0; mt < 4; ++mt)
    #pragma unroll
    for (int v = 0; v < 4; ++v) {
      int row = r0 + wr * 64 + mt * 16 + lg * 4 + v;
      #pragma unroll
      for (int nt = 0; nt < 4; ++nt) {
        int col = o0 + wc * 64 + nt * 16 + l15;
        pb[(size_t)row * EMBD + col] = acc[mt][nt][v];
      }
    }
}

// K6b: reduce partials + bias -> embv
__global__ __launch_bounds__(256) void k_bred(const float* __restrict__ part,
                                              const float* __restrict__ bilb,
                                              float* __restrict__ embv,
                                              int ksplit) {
  int idx = blockIdx.x * 256 + threadIdx.x;
  int o = idx - (idx / EMBD) * EMBD;
  float s = bilb[o];
  for (int zz = 0; zz < ksplit; ++zz) s += part[(size_t)zz * NP * EMBD + idx];
  embv[idx] = s;
}

// K7: rn = l2norm(r_emb_table @ re_W + re_b)
__global__ __launch_bounds__(256) void k_rel(const float* __restrict__ remb,
                                             const float* __restrict__ reW,
                                             const float* __restrict__ reb,
                                             float* __restrict__ rn) {
  int c = blockIdx.x;
  __shared__ float row_s[DD];
  int tid = threadIdx.x;
  for (int d = tid; d < DD; d += 256) row_s[d] = remb[(size_t)c * DD + d];
  __syncthreads();
  float v[3];
  float ss = 0.f;
  #pragma unroll
  for (int i = 0; i < 3; ++i) {
    int j = tid + i * 256;
    float acc = reb[j];
    for (int d = 0; d < DD; ++d) acc += row_s[d] * reW[(size_t)d * EMBD + j];
    v[i] = acc;
    ss += acc * acc;
  }
  float tot = blockReduceSum(ss);
  float scale = 1.f / fmaxf(sqrtf(tot), 1e-12f);
  #pragma unroll
  for (int i = 0; i < 3; ++i) rn[(size_t)c * EMBD + tid + i * 256] = v[i] * scale;
}

// K8: logits[r,c] = l2norm(emb[r]) . rn[c]
__global__ __launch_bounds__(128) void k_logits(const float* __restrict__ embv,
                                                const float* __restrict__ rn,
                                                float* __restrict__ out) {
  int r = blockIdx.x;
  __shared__ float row_s[EMBD];
  int tid = threadIdx.x;
  float ss = 0.f;
  for (int d = tid; d < EMBD; d += 128) {
    float x = embv[(size_t)r * EMBD + d];
    row_s[d] = x;
    ss += x * x;
  }
  float tot = blockReduceSum(ss);
  float inv = 1.f / fmaxf(sqrtf(tot), 1e-12f);
  if (tid < NCLS) {
    float acc = 0.f;
    for (int d = 0; d < DD; ++d) acc += row_s[d] * rn[(size_t)tid * EMBD + d];
    out[(size_t)r * NCLS + tid] = acc * inv;
  }
}

extern "C" void kernel_launch(void* const* d_in, const int* in_sizes, int n_in,
                              void* d_out, int out_size, void* d_ws, size_t ws_size,
                              hipStream_t stream) {
  const float* seq   = (const float*)d_in[0];
  const float* att   = (const float*)d_in[1];
  const int*   midx  = (const int*)d_in[2];
  const unsigned char* mask = (const unsigned char*)d_in[3];
  const int*   pairs = (const int*)d_in[4];
  const float* headW = (const float*)d_in[5];
  const float* headb = (const float*)d_in[6];
  const float* tailW = (const float*)d_in[7];
  const float* tailb = (const float*)d_in[8];
  const float* bilW  = (const float*)d_in[9];
  const float* bilb  = (const float*)d_in[10];
  const float* remb  = (const float*)d_in[11];
  const float* reW   = (const float*)d_in[12];
  const float* reb   = (const float*)d_in[13];
  float* out = (float*)d_out;

  float* w = (float*)d_ws;
  float* e_emb = w;  w += (size_t)NN * EE * DD;
  float* cntv  = w;  w += NN * EE;
  int*   vbuf  = (int*)w; w += NN * EE;
  float* e_att = w;  w += (size_t)NN * EE * HH * CC;     // 1,572,864 f
  float* ht    = w;  w += (size_t)NN * PP * CC;          // 1,048,576 f
  float* xh    = w;  w += (size_t)NP * K2D;              // 1,572,864 f
  float* xt    = w;  w += (size_t)NP * K2D;              // 1,572,864 f
  float* embv  = w;  w += (size_t)NP * EMBD;
  float* rn    = w;  w += (size_t)NCLS * EMBD;
  unsigned short* hsb = (unsigned short*)w;              // bf16 [1024][768]
  w += (size_t)NP * EMBD / 2;
  unsigned short* tsb = (unsigned short*)w;
  w += (size_t)NP * EMBD / 2;

  // KSPLIT=12 needs 12*NP*EMBD*4 = 37.75 MB of fresh ws beyond w;
  // fall back to KSPLIT=6 aliasing the dead e_att..xt region otherwise.
  size_t used = (size_t)((char*)w - (char*)d_ws);
  size_t need12 = (size_t)12 * NP * EMBD * sizeof(float);
  int ksplit; float* part;
  if (ws_size >= used + need12) { ksplit = 12; part = w; }
  else                          { ksplit = 6;  part = e_att; }
  int gpb = 12 / ksplit;
  int nslice = 6 * ksplit;
  int gridbil = 64 * ((nslice + 7) / 8);

  k_entity<<<NN * EE, 256, 0, stream>>>(seq, midx, mask, e_emb, cntv, vbuf);
  k_eatt<<<NN * EE * HH, 256, 0, stream>>>(att, midx, cntv, vbuf, e_att);
  k_ht<<<NN * PP, 256, 0, stream>>>(e_att, pairs, ht);
  k_fill<<<NP, 256, 0, stream>>>(e_emb, pairs, xh, xt);
  dim3 g4(PP / 64, DD / 64, NN);
  k_rs_mfma<<<g4, 256, 0, stream>>>(ht, seq, xh, xt);
  dim3 g5(NP / 64, EMBD / 128, 2);
  k_tanh_mfma<<<g5, 256, 0, stream>>>(xh, xt, headW, tailW, headb, tailb, hsb, tsb);
  k_bil_mfma<<<gridbil, 256, 0, stream>>>(hsb, tsb, bilW, part, nslice, gpb);
  k_bred<<<(NP * EMBD) / 256, 256, 0, stream>>>(part, bilb, embv, ksplit);
  k_rel<<<NCLS, 256, 0, stream>>>(remb, reW, reb, rn);
  k_logits<<<NP, 128, 0, stream>>>(embv, rn, out);
}